// Round 12
// baseline (16062.256 us; speedup 1.0000x reference)
//
#include <hip/hip_runtime.h>

// ACT RNN, T=8192, IO=32, H=256, M=4, EPS=0.01. f32 in/out.
// Round 12: MFMA act_chain, latency diet. Round 11 proved MFMA kills the
// VALU bloat (VALUBusy 0.244->0.067%) but ran 2000 cyc/iter: 2 barriers, a
// y->LDS round trip, and per-timestep U-prefetch drains. Fixes:
//  - tanh on C regs directly: C layout gives lane col rows w*64+col*16+quad*4+r
//    (16 identical B cols) -> owner lanes (col<4) handle 4 rows in-register.
//  - ONE barrier/iter: s-publish (ds_write_b64) + halting-dot plds ride the
//    same barrier, both ping-ponged by iter parity.
//  - U loads batched 8 timesteps (shifted +1 for the fused step0); acc/cum
//    stores batched 8 -> vmcnt drain ~once/16 iters.
// Speculative matvec + linearity (Ws·h = sum wn*y_n) from round 11 retained:
// step0 of each timestep needs no matvec. ws = 8.45 MB (acc_s aliases U).

#define T_  8192
#define IO_ 32
#define H_  256

typedef __attribute__((ext_vector_type(8))) __bf16 bf16x8;
typedef __attribute__((ext_vector_type(4))) float  f32x4;

__device__ __forceinline__ unsigned short f2bf(float f) {
    union { float f; unsigned int u; } v;
    v.f = f;
    unsigned int u = v.u;
    u += 0x7FFFu + ((u >> 16) & 1u);   // RNE
    return (unsigned short)(u >> 16);
}

template<int CTRL>
__device__ __forceinline__ float dpp_addf(float x) {
    int xi = __builtin_bit_cast(int, x);
    int d = __builtin_amdgcn_update_dpp(xi, xi, CTRL, 0xF, 0xF, false);
    return x + __builtin_bit_cast(float, d);
}

// full 64-lane sum -> valid in lane 63
__device__ __forceinline__ float wave_sum63(float x) {
    x = dpp_addf<0xB1>(x);    // quad_perm xor1
    x = dpp_addf<0x4E>(x);    // quad_perm xor2
    x = dpp_addf<0x124>(x);   // row_ror:4
    x = dpp_addf<0x128>(x);   // row_ror:8
    x = dpp_addf<0x142>(x);   // row_bcast15
    x = dpp_addf<0x143>(x);   // row_bcast31 -> lane63 total
    return x;
}

// ---------------- k_prep ----------------
__global__ void k_prep(const float* __restrict__ Wx,
                       const float* __restrict__ Wp,
                       const float* __restrict__ bp,
                       const float* __restrict__ b,
                       float* __restrict__ WxpT, float* __restrict__ cvec) {
    int h = blockIdx.x;
    int t = threadIdx.x;
    __shared__ float wxrow[H_];
    for (int j = t; j < H_; j += 64) wxrow[j] = Wx[h * (H_ + 1) + j];
    __syncthreads();
    if (t < IO_) {
        float acc = 0.0f;
        for (int j = 0; j < H_; ++j) acc += wxrow[j] * Wp[j * IO_ + t];
        WxpT[t * H_ + h] = acc;
    } else if (t == IO_) {
        float acc = b[h];
        for (int j = 0; j < H_; ++j) acc += wxrow[j] * bp[j];
        cvec[h] = acc;
    }
}

// ---------------- k_u ----------------
__global__ void k_u(const float* __restrict__ x,
                    const float* __restrict__ WxpT,
                    const float* __restrict__ cvec,
                    float* __restrict__ U) {
    int t0 = blockIdx.x * 8;
    int tid = threadIdx.x;
    __shared__ float xsf[8 * IO_];
    xsf[tid] = x[(size_t)t0 * IO_ + tid];
    __syncthreads();
    int h = tid;
    float base = cvec[h];
    for (int tt = 0; tt < 8; ++tt) {
        float acc = base;
        #pragma unroll
        for (int io = 0; io < IO_; ++io)
            acc += WxpT[io * H_ + h] * xsf[tt * IO_ + io];
        U[(size_t)(t0 + tt) * H_ + h] = acc;
    }
}

// ---------------- act_chain (MFMA, 1 barrier/iter) ----------------
__global__ __launch_bounds__(256, 1) void act_chain(
    const float* __restrict__ Ws,
    const float* __restrict__ Wx,
    const float* __restrict__ wh,
    const float* __restrict__ bh1,
    const float* __restrict__ h0,
    float* __restrict__ UAcc,
    float* __restrict__ cumArr,
    float* __restrict__ pc_out)
{
    __shared__ __align__(16) unsigned short sbuf[2][H_];  // s bf16, ping-pong
    __shared__ __align__(16) float plds[2][4];            // wave dot partials

    const int tid  = threadIdx.x;      // 0..255
    const int w    = tid >> 6;         // wave 0..3, rows [64w,64w+64)
    const int l    = tid & 63;
    const int quad = l >> 4;
    const int col  = l & 15;
    const bool owner = (col < 4);      // owner lane handles 4 rows in-register
    const int R0 = w * 64 + (owner ? col : 0) * 16 + quad * 4;

    // A-frags: Ws rows w*64+b*16+col, chunk c: 8 bf16 at c*32+quad*8
    bf16x8 af[4][8];
    #pragma unroll
    for (int b = 0; b < 4; ++b) {
        const float* row = Ws + (size_t)(w * 64 + b * 16 + col) * H_;
        #pragma unroll
        for (int c = 0; c < 8; ++c) {
            union { unsigned short u[8]; bf16x8 v; } tmp;
            #pragma unroll
            for (int j = 0; j < 8; ++j)
                tmp.u[j] = f2bf(row[c * 32 + quad * 8 + j]);
            af[b][c] = tmp.v;
        }
    }

    float wl4[4], whv4[4];
    #pragma unroll
    for (int r = 0; r < 4; ++r) {
        wl4[r]  = Wx[(size_t)(R0 + r) * (H_ + 1) + H_];  // first-step flag col
        whv4[r] = owner ? wh[R0 + r] : 0.0f;             // 0 => no dot pollution
    }
    const float bhf = bh1[0];
    const float thresh = 1.0f - 0.01f;
    const float L2E  = 1.4426950408889634f;
    const float L2E2 = 2.8853900817779268f;

    sbuf[0][tid] = f2bf(h0[tid]);
    __syncthreads();

    float sn4[4], ucur4[4], acc4[4], Wac4[4];
    float cum = 0.0f, nup = 1.0f, pc = 0.0f;
    int   P = 1;

    // ---- prolog: y = Ws·h0 via MFMA; fused step0 of t=0 ----
    {
        f32x4 C0 = {0,0,0,0}, C1 = C0, C2 = C0, C3 = C0;
        #pragma unroll
        for (int c = 0; c < 8; ++c) {
            bf16x8 bf = *reinterpret_cast<const bf16x8*>(
                (const char*)&sbuf[0][0] + c * 64 + quad * 16);
            C0 = __builtin_amdgcn_mfma_f32_16x16x32_bf16(af[0][c], bf, C0, 0, 0, 0);
            C1 = __builtin_amdgcn_mfma_f32_16x16x32_bf16(af[1][c], bf, C1, 0, 0, 0);
            C2 = __builtin_amdgcn_mfma_f32_16x16x32_bf16(af[2][c], bf, C2, 0, 0, 0);
            C3 = __builtin_amdgcn_mfma_f32_16x16x32_bf16(af[3][c], bf, C3, 0, 0, 0);
        }
        float4 u0 = *(const float4*)(UAcc + R0);
        ucur4[0] = u0.x; ucur4[1] = u0.y; ucur4[2] = u0.z; ucur4[3] = u0.w;
        float part = 0.0f;
        #pragma unroll
        for (int r = 0; r < 4; ++r) {
            float y = (col == 0) ? C0[r] : (col == 1) ? C1[r]
                    : (col == 2) ? C2[r] : C3[r];
            float a = ucur4[r] + wl4[r] + y;
            float e = __builtin_amdgcn_exp2f(a * L2E2);
            sn4[r] = __builtin_fmaf(-2.0f, __builtin_amdgcn_rcpf(e + 1.0f), 1.0f);
            part = __builtin_fmaf(whv4[r], sn4[r], part);
            acc4[r] = 0.0f; Wac4[r] = 0.0f;
        }
        if (owner) {
            uint2 pk;
            pk.x = (unsigned)f2bf(sn4[0]) | ((unsigned)f2bf(sn4[1]) << 16);
            pk.y = (unsigned)f2bf(sn4[2]) | ((unsigned)f2bf(sn4[3]) << 16);
            *(uint2*)(&sbuf[1][R0]) = pk;
        }
        part = wave_sum63(part);
        if (l == 63) plds[1][w] = part;
        __syncthreads();
    }

    #pragma unroll 1
    for (int g = 0; g < T_ / 8; ++g) {
        // batched u prefetch, shifted +1 (consumed by fused step0 of t+1)
        float4 un[8];
        #pragma unroll
        for (int j = 0; j < 8; ++j) {
            int tn = g * 8 + 1 + j;
            if (tn > T_ - 1) tn = T_ - 1;
            un[j] = *(const float4*)(UAcc + (size_t)tn * H_ + R0);
        }
        float4 av[8];
        float  cu8[8];

        #pragma unroll
        for (int j = 0; j < 8; ++j) {
            #pragma unroll 1
            for (int k = 1; k <= 4; ++k) {
                f32x4 pv = *(const f32x4*)(&plds[P][0]);   // dot partials of s_k
                f32x4 C0 = {0,0,0,0}, C1 = C0, C2 = C0, C3 = C0;
                #pragma unroll
                for (int c = 0; c < 8; ++c) {
                    bf16x8 bf = *reinterpret_cast<const bf16x8*>(
                        (const char*)&sbuf[P][0] + c * 64 + quad * 16);
                    C0 = __builtin_amdgcn_mfma_f32_16x16x32_bf16(af[0][c], bf, C0, 0, 0, 0);
                    C1 = __builtin_amdgcn_mfma_f32_16x16x32_bf16(af[1][c], bf, C1, 0, 0, 0);
                    C2 = __builtin_amdgcn_mfma_f32_16x16x32_bf16(af[2][c], bf, C2, 0, 0, 0);
                    C3 = __builtin_amdgcn_mfma_f32_16x16x32_bf16(af[3][c], bf, C3, 0, 0, 0);
                }
                float y4[4];
                #pragma unroll
                for (int r = 0; r < 4; ++r)
                    y4[r] = (col == 0) ? C0[r] : (col == 1) ? C1[r]
                          : (col == 2) ? C2[r] : C3[r];

                float dot = (pv[0] + pv[1]) + (pv[2] + pv[3]);
                float p = __builtin_amdgcn_rcpf(
                    1.0f + __builtin_amdgcn_exp2f(-(dot + bhf) * L2E));
                bool halt = (cum + p > thresh) || (k == 4);
                float hw = 1.0f - cum;
                float wn = halt ? hw : p;
                #pragma unroll
                for (int r = 0; r < 4; ++r) {
                    acc4[r] = __builtin_fmaf(wn, sn4[r], acc4[r]);
                    Wac4[r] = __builtin_fmaf(wn, y4[r], Wac4[r]);
                }
                cum += wn;

                if (halt) {
                    // close timestep t=g*8+j, fused step0 of t+1
                    pc = (pc + nup + hw) * (1.0f / (float)T_);
                    av[j]  = make_float4(acc4[0], acc4[1], acc4[2], acc4[3]);
                    cu8[j] = cum;
                    const float* up = (const float*)&un[j];
                    float part = 0.0f;
                    #pragma unroll
                    for (int r = 0; r < 4; ++r) {
                        float a = up[r] + wl4[r] + Wac4[r];   // Ws·h by linearity
                        float e = __builtin_amdgcn_exp2f(a * L2E2);
                        sn4[r] = __builtin_fmaf(-2.0f, __builtin_amdgcn_rcpf(e + 1.0f), 1.0f);
                        part = __builtin_fmaf(whv4[r], sn4[r], part);
                        ucur4[r] = up[r];
                        acc4[r] = 0.0f; Wac4[r] = 0.0f;
                    }
                    if (owner) {
                        uint2 pk;
                        pk.x = (unsigned)f2bf(sn4[0]) | ((unsigned)f2bf(sn4[1]) << 16);
                        pk.y = (unsigned)f2bf(sn4[2]) | ((unsigned)f2bf(sn4[3]) << 16);
                        *(uint2*)(&sbuf[P ^ 1][R0]) = pk;
                    }
                    part = wave_sum63(part);
                    if (l == 63) plds[P ^ 1][w] = part;
                    cum = 0.0f; nup = 1.0f;
                    P ^= 1;
                    __syncthreads();
                    break;
                } else {
                    float part = 0.0f;
                    #pragma unroll
                    for (int r = 0; r < 4; ++r) {
                        float a = ucur4[r] + y4[r];
                        float e = __builtin_amdgcn_exp2f(a * L2E2);
                        sn4[r] = __builtin_fmaf(-2.0f, __builtin_amdgcn_rcpf(e + 1.0f), 1.0f);
                        part = __builtin_fmaf(whv4[r], sn4[r], part);
                    }
                    if (owner) {
                        uint2 pk;
                        pk.x = (unsigned)f2bf(sn4[0]) | ((unsigned)f2bf(sn4[1]) << 16);
                        pk.y = (unsigned)f2bf(sn4[2]) | ((unsigned)f2bf(sn4[3]) << 16);
                        *(uint2*)(&sbuf[P ^ 1][R0]) = pk;
                    }
                    part = wave_sum63(part);
                    if (l == 63) plds[P ^ 1][w] = part;
                    nup += 1.0f;
                    P ^= 1;
                    __syncthreads();
                }
            }
        }

        // batched stores: acc_s (in place over dead U rows) + cum
        if (owner) {
            #pragma unroll
            for (int j = 0; j < 8; ++j)
                *(float4*)(UAcc + (size_t)(g * 8 + j) * H_ + R0) = av[j];
        }
        if (tid == 0) {
            #pragma unroll
            for (int j = 0; j < 8; ++j) cumArr[g * 8 + j] = cu8[j];
        }
    }
    if (tid == 0) pc_out[0] = pc;
}

// ---------------- k_out ----------------
__global__ void k_out(const float* __restrict__ AccS,
                      const float* __restrict__ Wo,
                      const float* __restrict__ bo,
                      const float* __restrict__ cumArr,
                      float* __restrict__ ys) {
    int t0 = blockIdx.x * 8;
    int tid = threadIdx.x;   // 256
    __shared__ float wo[IO_ * 257];
    __shared__ float as[8 * 260];
    for (int i = tid; i < IO_ * H_; i += 256) {
        int o = i / H_, h = i % H_;
        wo[o * 257 + h] = Wo[i];
    }
    for (int i = tid; i < 8 * H_; i += 256) {
        int tt = i / H_, h = i % H_;
        as[tt * 260 + h] = AccS[(size_t)t0 * H_ + i];
    }
    __syncthreads();
    int tt = tid >> 5, o = tid & 31;
    float acc = cumArr[t0 + tt] * bo[o];
    #pragma unroll 4
    for (int h = 0; h < H_; ++h) acc += wo[o * 257 + h] * as[tt * 260 + h];
    ys[(size_t)(t0 + tt) * IO_ + o] = acc;
}

extern "C" void kernel_launch(void* const* d_in, const int* in_sizes, int n_in,
                              void* d_out, int out_size, void* d_ws, size_t ws_size,
                              hipStream_t stream) {
    const float* x  = (const float*)d_in[0];
    const float* h0 = (const float*)d_in[1];
    const float* Wp = (const float*)d_in[2];
    const float* bp = (const float*)d_in[3];
    const float* Wx = (const float*)d_in[4];
    const float* Ws = (const float*)d_in[5];
    const float* b  = (const float*)d_in[6];
    const float* wh = (const float*)d_in[7];
    const float* bh = (const float*)d_in[8];
    const float* Wo = (const float*)d_in[9];
    const float* bo = (const float*)d_in[10];
    float* out = (float*)d_out;   // f32: ys[8192*32] then pc

    char* ws = (char*)d_ws;
    float* WxpT = (float*)ws;                                    //  32 KB
    float* cvec = (float*)(ws + 32768);                          //   1 KB
    float* cumA = (float*)(ws + 33792);                          //  32 KB
    float* UAcc = (float*)(ws + 66560);                          //   8 MB f32
    // total ws use: 8.45 MB (acc_s aliases UAcc in place)

    k_prep<<<H_, 64, 0, stream>>>(Wx, Wp, bp, b, WxpT, cvec);
    k_u<<<T_ / 8, 256, 0, stream>>>(x, WxpT, cvec, UAcc);
    act_chain<<<1, 256, 0, stream>>>(Ws, Wx, wh, bh, h0, UAcc, cumA,
                                     out + (size_t)T_ * IO_);
    k_out<<<T_ / 8, 256, 0, stream>>>(UAcc, Wo, bo, cumA, out);
}

// Round 13
// 13098.840 us; speedup vs baseline: 1.2262x; 1.2262x over previous
//
#include <hip/hip_runtime.h>

// ACT RNN, T=8192, IO=32, H=256, M=4, EPS=0.01. f32 in/out.
// Round 13: MFMA act_chain at 2 waves/SIMD. Round 12 (4 waves = 1/SIMD) was
// stall-bound: MfmaUtil 22%/VALU 37% of the one CU, rest idle latency
// (post-barrier ds_read ~120cyc, DPP chains, exp2 chains) with no second
// wave to co-issue. Now 512 thr / 8 waves, 32 rows/wave = 2 row-blocks x
// 8 K-chunks = 16 MFMA/wave/iter (A-frags 64 VGPR). launch_bounds(512,2)
// caps VGPR at 256 so both waves/SIMD are resident. Keeps r12's: 1 barrier
// per iter, fused step0 via linearity (Ws·h = sum wn*y_n), batched U/acc IO.
// ws = 8.45 MB (acc_s aliases U in place).

#define T_  8192
#define IO_ 32
#define H_  256

typedef __attribute__((ext_vector_type(8))) __bf16 bf16x8;
typedef __attribute__((ext_vector_type(4))) float  f32x4;

__device__ __forceinline__ unsigned short f2bf(float f) {
    union { float f; unsigned int u; } v;
    v.f = f;
    unsigned int u = v.u;
    u += 0x7FFFu + ((u >> 16) & 1u);   // RNE
    return (unsigned short)(u >> 16);
}

template<int CTRL>
__device__ __forceinline__ float dpp_addf(float x) {
    int xi = __builtin_bit_cast(int, x);
    int d = __builtin_amdgcn_update_dpp(xi, xi, CTRL, 0xF, 0xF, false);
    return x + __builtin_bit_cast(float, d);
}

// full 64-lane sum -> valid in lane 63
__device__ __forceinline__ float wave_sum63(float x) {
    x = dpp_addf<0xB1>(x);
    x = dpp_addf<0x4E>(x);
    x = dpp_addf<0x124>(x);
    x = dpp_addf<0x128>(x);
    x = dpp_addf<0x142>(x);
    x = dpp_addf<0x143>(x);
    return x;
}

// ---------------- k_prep ----------------
__global__ void k_prep(const float* __restrict__ Wx,
                       const float* __restrict__ Wp,
                       const float* __restrict__ bp,
                       const float* __restrict__ b,
                       float* __restrict__ WxpT, float* __restrict__ cvec) {
    int h = blockIdx.x;
    int t = threadIdx.x;
    __shared__ float wxrow[H_];
    for (int j = t; j < H_; j += 64) wxrow[j] = Wx[h * (H_ + 1) + j];
    __syncthreads();
    if (t < IO_) {
        float acc = 0.0f;
        for (int j = 0; j < H_; ++j) acc += wxrow[j] * Wp[j * IO_ + t];
        WxpT[t * H_ + h] = acc;
    } else if (t == IO_) {
        float acc = b[h];
        for (int j = 0; j < H_; ++j) acc += wxrow[j] * bp[j];
        cvec[h] = acc;
    }
}

// ---------------- k_u ----------------
__global__ void k_u(const float* __restrict__ x,
                    const float* __restrict__ WxpT,
                    const float* __restrict__ cvec,
                    float* __restrict__ U) {
    int t0 = blockIdx.x * 8;
    int tid = threadIdx.x;
    __shared__ float xsf[8 * IO_];
    xsf[tid] = x[(size_t)t0 * IO_ + tid];
    __syncthreads();
    int h = tid;
    float base = cvec[h];
    for (int tt = 0; tt < 8; ++tt) {
        float acc = base;
        #pragma unroll
        for (int io = 0; io < IO_; ++io)
            acc += WxpT[io * H_ + h] * xsf[tt * IO_ + io];
        U[(size_t)(t0 + tt) * H_ + h] = acc;
    }
}

// ---------------- act_chain (MFMA, 8 waves = 2/SIMD, 1 barrier/iter) -------
__global__ __launch_bounds__(512, 2) void act_chain(
    const float* __restrict__ Ws,
    const float* __restrict__ Wx,
    const float* __restrict__ wh,
    const float* __restrict__ bh1,
    const float* __restrict__ h0,
    float* __restrict__ UAcc,
    float* __restrict__ cumArr,
    float* __restrict__ pc_out)
{
    __shared__ __align__(16) unsigned short sbuf[2][H_];  // s bf16, ping-pong
    __shared__ __align__(16) float plds[2][8];            // wave dot partials

    const int tid  = threadIdx.x;      // 0..511
    const int w    = tid >> 6;         // wave 0..7, rows [32w, 32w+32)
    const int l    = tid & 63;
    const int quad = l >> 4;
    const int col  = l & 15;
    const bool owner = (col < 2);      // owner col b handles block b, 4 rows
    const int R0 = w * 32 + (owner ? col : 0) * 16 + quad * 4;

    // A-frags: Ws rows w*32+b*16+col, chunk c: 8 bf16 at c*32+quad*8
    bf16x8 af[2][8];
    #pragma unroll
    for (int b = 0; b < 2; ++b) {
        const float* row = Ws + (size_t)(w * 32 + b * 16 + col) * H_;
        #pragma unroll
        for (int c = 0; c < 8; ++c) {
            union { unsigned short u[8]; bf16x8 v; } tmp;
            #pragma unroll
            for (int j = 0; j < 8; ++j)
                tmp.u[j] = f2bf(row[c * 32 + quad * 8 + j]);
            af[b][c] = tmp.v;
        }
    }

    float wl4[4], whv4[4];
    #pragma unroll
    for (int r = 0; r < 4; ++r) {
        wl4[r]  = Wx[(size_t)(R0 + r) * (H_ + 1) + H_];  // first-step flag col
        whv4[r] = owner ? wh[R0 + r] : 0.0f;
    }
    const float bhf = bh1[0];
    const float thresh = 1.0f - 0.01f;
    const float L2E  = 1.4426950408889634f;
    const float L2E2 = 2.8853900817779268f;

    if (tid < H_) sbuf[0][tid] = f2bf(h0[tid]);
    __syncthreads();

    float sn4[4], ucur4[4], acc4[4], Wac4[4];
    float cum = 0.0f, nup = 1.0f, pc = 0.0f;
    int   P = 1;

    // ---- prolog: y = Ws·h0; fused step0 of t=0 ----
    {
        f32x4 C0 = {0,0,0,0}, C1 = C0;
        #pragma unroll
        for (int c = 0; c < 8; ++c) {
            bf16x8 bf = *reinterpret_cast<const bf16x8*>(
                (const char*)&sbuf[0][0] + c * 64 + quad * 16);
            C0 = __builtin_amdgcn_mfma_f32_16x16x32_bf16(af[0][c], bf, C0, 0, 0, 0);
            C1 = __builtin_amdgcn_mfma_f32_16x16x32_bf16(af[1][c], bf, C1, 0, 0, 0);
        }
        float4 u0 = *(const float4*)(UAcc + R0);
        ucur4[0] = u0.x; ucur4[1] = u0.y; ucur4[2] = u0.z; ucur4[3] = u0.w;
        float part = 0.0f;
        #pragma unroll
        for (int r = 0; r < 4; ++r) {
            float y = (col == 0) ? C0[r] : C1[r];
            float a = ucur4[r] + wl4[r] + y;
            float e = __builtin_amdgcn_exp2f(a * L2E2);
            sn4[r] = __builtin_fmaf(-2.0f, __builtin_amdgcn_rcpf(e + 1.0f), 1.0f);
            part = __builtin_fmaf(whv4[r], sn4[r], part);
            acc4[r] = 0.0f; Wac4[r] = 0.0f;
        }
        if (owner) {
            uint2 pk;
            pk.x = (unsigned)f2bf(sn4[0]) | ((unsigned)f2bf(sn4[1]) << 16);
            pk.y = (unsigned)f2bf(sn4[2]) | ((unsigned)f2bf(sn4[3]) << 16);
            *(uint2*)(&sbuf[1][R0]) = pk;
        }
        part = wave_sum63(part);
        if (l == 63) plds[1][w] = part;
        __syncthreads();
    }

    #pragma unroll 1
    for (int g = 0; g < T_ / 8; ++g) {
        // batched u prefetch, shifted +1 (consumed by fused step0 of t+1)
        float4 un[8];
        #pragma unroll
        for (int j = 0; j < 8; ++j) {
            int tn = g * 8 + 1 + j;
            if (tn > T_ - 1) tn = T_ - 1;
            un[j] = *(const float4*)(UAcc + (size_t)tn * H_ + R0);
        }
        float4 av[8];
        float  cu8[8];

        #pragma unroll
        for (int j = 0; j < 8; ++j) {
            #pragma unroll 1
            for (int k = 1; k <= 4; ++k) {
                f32x4 pa = *(const f32x4*)(&plds[P][0]);
                f32x4 pb = *(const f32x4*)(&plds[P][4]);
                f32x4 C0 = {0,0,0,0}, C1 = C0;
                #pragma unroll
                for (int c = 0; c < 8; ++c) {
                    bf16x8 bf = *reinterpret_cast<const bf16x8*>(
                        (const char*)&sbuf[P][0] + c * 64 + quad * 16);
                    C0 = __builtin_amdgcn_mfma_f32_16x16x32_bf16(af[0][c], bf, C0, 0, 0, 0);
                    C1 = __builtin_amdgcn_mfma_f32_16x16x32_bf16(af[1][c], bf, C1, 0, 0, 0);
                }
                float y4[4];
                #pragma unroll
                for (int r = 0; r < 4; ++r)
                    y4[r] = (col == 0) ? C0[r] : C1[r];

                float dot = ((pa[0] + pa[1]) + (pa[2] + pa[3])) +
                            ((pb[0] + pb[1]) + (pb[2] + pb[3]));
                float p = __builtin_amdgcn_rcpf(
                    1.0f + __builtin_amdgcn_exp2f(-(dot + bhf) * L2E));
                bool halt = (cum + p > thresh) || (k == 4);
                float hw = 1.0f - cum;
                float wn = halt ? hw : p;
                #pragma unroll
                for (int r = 0; r < 4; ++r) {
                    acc4[r] = __builtin_fmaf(wn, sn4[r], acc4[r]);
                    Wac4[r] = __builtin_fmaf(wn, y4[r], Wac4[r]);
                }
                cum += wn;

                if (halt) {
                    // close timestep t=g*8+j, fused step0 of t+1
                    pc = (pc + nup + hw) * (1.0f / (float)T_);
                    av[j]  = make_float4(acc4[0], acc4[1], acc4[2], acc4[3]);
                    cu8[j] = cum;
                    const float* up = (const float*)&un[j];
                    float part = 0.0f;
                    #pragma unroll
                    for (int r = 0; r < 4; ++r) {
                        float a = up[r] + wl4[r] + Wac4[r];   // Ws·h by linearity
                        float e = __builtin_amdgcn_exp2f(a * L2E2);
                        sn4[r] = __builtin_fmaf(-2.0f, __builtin_amdgcn_rcpf(e + 1.0f), 1.0f);
                        part = __builtin_fmaf(whv4[r], sn4[r], part);
                        ucur4[r] = up[r];
                        acc4[r] = 0.0f; Wac4[r] = 0.0f;
                    }
                    if (owner) {
                        uint2 pk;
                        pk.x = (unsigned)f2bf(sn4[0]) | ((unsigned)f2bf(sn4[1]) << 16);
                        pk.y = (unsigned)f2bf(sn4[2]) | ((unsigned)f2bf(sn4[3]) << 16);
                        *(uint2*)(&sbuf[P ^ 1][R0]) = pk;
                    }
                    part = wave_sum63(part);
                    if (l == 63) plds[P ^ 1][w] = part;
                    cum = 0.0f; nup = 1.0f;
                    P ^= 1;
                    __syncthreads();
                    break;
                } else {
                    float part = 0.0f;
                    #pragma unroll
                    for (int r = 0; r < 4; ++r) {
                        float a = ucur4[r] + y4[r];
                        float e = __builtin_amdgcn_exp2f(a * L2E2);
                        sn4[r] = __builtin_fmaf(-2.0f, __builtin_amdgcn_rcpf(e + 1.0f), 1.0f);
                        part = __builtin_fmaf(whv4[r], sn4[r], part);
                    }
                    if (owner) {
                        uint2 pk;
                        pk.x = (unsigned)f2bf(sn4[0]) | ((unsigned)f2bf(sn4[1]) << 16);
                        pk.y = (unsigned)f2bf(sn4[2]) | ((unsigned)f2bf(sn4[3]) << 16);
                        *(uint2*)(&sbuf[P ^ 1][R0]) = pk;
                    }
                    part = wave_sum63(part);
                    if (l == 63) plds[P ^ 1][w] = part;
                    nup += 1.0f;
                    P ^= 1;
                    __syncthreads();
                }
            }
        }

        // batched stores: acc_s (in place over dead U rows) + cum
        if (owner) {
            #pragma unroll
            for (int j = 0; j < 8; ++j)
                *(float4*)(UAcc + (size_t)(g * 8 + j) * H_ + R0) = av[j];
        }
        if (tid == 0) {
            #pragma unroll
            for (int j = 0; j < 8; ++j) cumArr[g * 8 + j] = cu8[j];
        }
    }
    if (tid == 0) pc_out[0] = pc;
}

// ---------------- k_out ----------------
__global__ void k_out(const float* __restrict__ AccS,
                      const float* __restrict__ Wo,
                      const float* __restrict__ bo,
                      const float* __restrict__ cumArr,
                      float* __restrict__ ys) {
    int t0 = blockIdx.x * 8;
    int tid = threadIdx.x;   // 256
    __shared__ float wo[IO_ * 257];
    __shared__ float as[8 * 260];
    for (int i = tid; i < IO_ * H_; i += 256) {
        int o = i / H_, h = i % H_;
        wo[o * 257 + h] = Wo[i];
    }
    for (int i = tid; i < 8 * H_; i += 256) {
        int tt = i / H_, h = i % H_;
        as[tt * 260 + h] = AccS[(size_t)t0 * H_ + i];
    }
    __syncthreads();
    int tt = tid >> 5, o = tid & 31;
    float acc = cumArr[t0 + tt] * bo[o];
    #pragma unroll 4
    for (int h = 0; h < H_; ++h) acc += wo[o * 257 + h] * as[tt * 260 + h];
    ys[(size_t)(t0 + tt) * IO_ + o] = acc;
}

extern "C" void kernel_launch(void* const* d_in, const int* in_sizes, int n_in,
                              void* d_out, int out_size, void* d_ws, size_t ws_size,
                              hipStream_t stream) {
    const float* x  = (const float*)d_in[0];
    const float* h0 = (const float*)d_in[1];
    const float* Wp = (const float*)d_in[2];
    const float* bp = (const float*)d_in[3];
    const float* Wx = (const float*)d_in[4];
    const float* Ws = (const float*)d_in[5];
    const float* b  = (const float*)d_in[6];
    const float* wh = (const float*)d_in[7];
    const float* bh = (const float*)d_in[8];
    const float* Wo = (const float*)d_in[9];
    const float* bo = (const float*)d_in[10];
    float* out = (float*)d_out;   // f32: ys[8192*32] then pc

    char* ws = (char*)d_ws;
    float* WxpT = (float*)ws;                                    //  32 KB
    float* cvec = (float*)(ws + 32768);                          //   1 KB
    float* cumA = (float*)(ws + 33792);                          //  32 KB
    float* UAcc = (float*)(ws + 66560);                          //   8 MB f32
    // total ws use: 8.45 MB (acc_s aliases UAcc in place)

    k_prep<<<H_, 64, 0, stream>>>(Wx, Wp, bp, b, WxpT, cvec);
    k_u<<<T_ / 8, 256, 0, stream>>>(x, WxpT, cvec, UAcc);
    act_chain<<<1, 512, 0, stream>>>(Ws, Wx, wh, bh, h0, UAcc, cumA,
                                     out + (size_t)T_ * IO_);
    k_out<<<T_ / 8, 256, 0, stream>>>(UAcc, Wo, bo, cumA, out);
}